// Round 2
// baseline (1295.609 us; speedup 1.0000x reference)
//
#include <hip/hip_runtime.h>
#include <hip/hip_fp16.h>

#define IN_F   8192
#define OUT_F  28672
#define NFP    128
#define NB     32            // B*S rows
#define KQTOT  (IN_F / 4)    // 2048 packed dwords per weight/batch row

#define KC     4             // split-K factor
#define KCHUNK (IN_F / KC)   // 2048 k per block

// ws layout (bytes):
//   q_pk : int  [NB][KQTOT]                       [0, 262144)
//   xs   : float[32]                              [262144, ...)
//   act  : float[32][128]                         [263168, 279552)
//   part : int  [KC][NB][OUT_F] (14,680,064 B)    [524288, 15204352)
//   w_pk : int  [OUT_F][KQTOT] (234,881,024 B)    [16777216, 251658240)
#define WS_QPK  0
#define WS_XS   262144
#define WS_ACT  263168
#define WS_PART 524288
#define WS_WPK  16777216

typedef int v4i  __attribute__((ext_vector_type(4)));
typedef int v16i __attribute__((ext_vector_type(16)));

__device__ __forceinline__ int pack8(int4 v) {
    return (v.x & 0xFF) | ((v.y & 0xFF) << 8) | ((v.z & 0xFF) << 16) | (v.w << 24);
}

// ---------------- Kernel A: dynamic quantization (unchanged) ----------------
__global__ __launch_bounds__(256) void quant_kernel(
    const float* __restrict__ x, const int* __restrict__ ind,
    int* __restrict__ q_pk, float* __restrict__ xs_out,
    float* __restrict__ act_out)
{
    __shared__ unsigned char flags[IN_F];   // 8 KB
    __shared__ float redbuf[4];
    __shared__ float xs_sh;
    const int tid = threadIdx.x;
    const int b = blockIdx.x;

    int* fl4 = (int*)flags;
    for (int i = tid; i < IN_F / 4; i += 256) fl4[i] = 0;
    __syncthreads();
    if (tid < NFP) flags[ind[tid]] = 1;
    __syncthreads();

    const float* xrow = x + (size_t)b * IN_F;
    const float4* x4 = (const float4*)xrow;
    float mx = 0.f;
    for (int c = tid; c < IN_F / 4; c += 256) {
        float4 v = x4[c];
        int fw = fl4[c];
        if (!(fw & 0x000000FF)) mx = fmaxf(mx, fabsf(v.x));
        if (!(fw & 0x0000FF00)) mx = fmaxf(mx, fabsf(v.y));
        if (!(fw & 0x00FF0000)) mx = fmaxf(mx, fabsf(v.z));
        if (!(fw & 0xFF000000)) mx = fmaxf(mx, fabsf(v.w));
    }
    #pragma unroll
    for (int off = 32; off > 0; off >>= 1) {
        float o = __shfl_down(mx, off, 64);
        mx = o > mx ? o : mx;
    }
    if ((tid & 63) == 0) redbuf[tid >> 6] = mx;
    __syncthreads();
    if (tid == 0) {
        float m = redbuf[0];
        #pragma unroll
        for (int i = 1; i < 4; i++) m = redbuf[i] > m ? redbuf[i] : m;
        float xs = __half2float(__float2half_rn(m / 127.0f));   // x_scale = f16(max/127)
        xs_sh = xs;
        xs_out[b] = xs;
    }
    __syncthreads();
    const float xs = xs_sh;

    for (int c = tid; c < IN_F / 4; c += 256) {
        float4 v = x4[c];
        int fw = fl4[c];
        float ee[4];
        ee[0] = (fw & 0x000000FF) ? 0.f : v.x;
        ee[1] = (fw & 0x0000FF00) ? 0.f : v.y;
        ee[2] = (fw & 0x00FF0000) ? 0.f : v.z;
        ee[3] = (fw & 0xFF000000) ? 0.f : v.w;
        int pk = 0;
        #pragma unroll
        for (int j = 0; j < 4; j++) {
            float qf = __half2float(__float2half_rn(ee[j] / xs));
            float r = rintf(qf);
            r = fminf(fmaxf(r, -128.f), 127.f);
            int qi = (int)r;
            pk |= (qi & 0xFF) << (8 * j);
        }
        q_pk[(size_t)b * KQTOT + c] = pk;
    }
    if (tid < NFP) act_out[b * NFP + tid] = xrow[ind[tid]];
}

// ---------------- Kernel R: weight repack int32 -> packed int8 ----------------
// Pure streaming transform: per wave-iteration, 64 lanes read 4x 1024-B
// contiguous segments (instr j: lanes at src[j*64+lane], fully coalesced)
// and write 4x 256-B contiguous dword segments. Output dword index ==
// input int4 index, so order is preserved exactly.
__global__ __launch_bounds__(256) void repack_kernel(
    const int* __restrict__ w, int* __restrict__ wpk)
{
    const int gtid = blockIdx.x * 256 + threadIdx.x;
    const int wid  = gtid >> 6;
    const int lane = gtid & 63;
    const int nwave = (gridDim.x * 256) >> 6;
    const size_t total4 = (size_t)OUT_F * (IN_F / 4);   // 58,720,256 input int4s

    for (size_t base = (size_t)wid * 256; base < total4; base += (size_t)nwave * 256) {
        const int4* src = (const int4*)w + base;
        int outd[4];
        #pragma unroll
        for (int j = 0; j < 4; j++) {
            int4 v = src[j * 64 + lane];
            outd[j] = pack8(v);
        }
        int* dst = wpk + base;
        #pragma unroll
        for (int j = 0; j < 4; j++) dst[j * 64 + lane] = outd[j];
    }
}

// ---------------- Kernel B: split-K MFMA int8 GEMM on packed weights ----------------
#define OT    64          // outputs per block (32 per wave, 2 waves)
#define KT    256         // k per tile
#define WROW  68          // padded row stride in dwords (uniform bank spread)
#define QROW  68
#define NTILE (KCHUNK / KT)   // 8 tiles per block

__device__ __forceinline__ void stage_tiles(
    const int* __restrict__ wpk, const int* __restrict__ q_pk,
    int* __restrict__ wp, int* __restrict__ qt,
    int tid, int blk_o, int kd0)     // kd0 = k offset in packed dwords
{
    // W tile: 64 rows x 64 packed dwords (16x int4 chunks per row).
    // 16 lanes cover one row's 256 B contiguously -> coalesced.
    #pragma unroll
    for (int i = 0; i < 8; i++) {
        int u = i * 128 + tid;
        int r = u >> 4;           // row 0..63
        int c = u & 15;           // 16-B chunk 0..15
        int4 v = *(const int4*)(wpk + (size_t)(blk_o + r) * KQTOT + kd0 + c * 4);
        *(int4*)&wp[r * WROW + c * 4] = v;
    }
    // q tile: 32 batches x 64 packed dwords
    #pragma unroll
    for (int i = 0; i < 4; i++) {
        int u  = i * 128 + tid;
        int bb = u >> 4;          // batch 0..31
        int c  = u & 15;
        int4 v = *(const int4*)(q_pk + (size_t)bb * KQTOT + kd0 + c * 4);
        *(int4*)&qt[bb * QROW + c * 4] = v;
    }
}

__global__ __launch_bounds__(128) void gemm_kernel(
    const int* __restrict__ wpk, const int* __restrict__ q_pk,
    int* __restrict__ part)
{
    __shared__ int w_p[2][OT * WROW] __attribute__((aligned(16)));   // 2 x 17408 B
    __shared__ int q_t[2][NB * QROW] __attribute__((aligned(16)));   // 2 x  8704 B

    const int tid  = threadIdx.x;
    const int wave = tid >> 6;
    const int lane = tid & 63;
    const int nl   = lane & 31;     // output column within wave tile
    const int half = lane >> 5;     // k-half selector for A/B fragments

    const int kc    = blockIdx.x & (KC - 1);
    const int blk_o = (blockIdx.x >> 2) * OT;
    const int kdbase = kc * (KCHUNK / 4);   // packed-dword base
    const int n = blk_o + wave * 32 + nl;

    v16i acc;
    #pragma unroll
    for (int r = 0; r < 16; r++) acc[r] = 0;

    stage_tiles(wpk, q_pk, w_p[0], q_t[0], tid, blk_o, kdbase);
    __syncthreads();

    for (int t = 0; t < NTILE; ++t) {
        const int cur = t & 1;
        if (t + 1 < NTILE)
            stage_tiles(wpk, q_pk, w_p[cur ^ 1], q_t[cur ^ 1],
                        tid, blk_o, kdbase + (t + 1) * (KT / 4));

        const int* qrow = &q_t[cur][nl * QROW + half * 4];
        const int* wrow = &w_p[cur][(wave * 32 + nl) * WROW + half * 4];
        #pragma unroll
        for (int s = 0; s < KT / 32; s++) {
            v4i a = *(const v4i*)(qrow + s * 8);   // ds_read_b128
            v4i b = *(const v4i*)(wrow + s * 8);   // ds_read_b128
            acc = __builtin_amdgcn_mfma_i32_32x32x32_i8(a, b, acc, 0, 0, 0);
        }
        __syncthreads();
    }

    // int32 partials (exact); epilogue kernel reduces across kc
    #pragma unroll
    for (int r = 0; r < 16; r++) {
        int b = (r & 3) + 8 * (r >> 2) + 4 * half;   // C/D row = batch
        part[((size_t)kc * NB + b) * OUT_F + n] = acc[r];
    }
}

// ---------------- Kernel C: reduce partials + f32 epilogue ----------------
__global__ __launch_bounds__(256) void epilogue_kernel(
    const int* __restrict__ part, const float* __restrict__ xs_ws,
    const float* __restrict__ act_ws, const float* __restrict__ sc,
    const float* __restrict__ wc, const float* __restrict__ bias,
    float* __restrict__ out)
{
    __shared__ float act_l[NB * NFP];   // 16 KB
    __shared__ float xs_l[NB];
    const int tid = threadIdx.x;
    const int blk_o = blockIdx.x * 64;

    for (int i = tid; i < NB * NFP; i += 256) act_l[i] = act_ws[i];
    if (tid < NB) xs_l[tid] = xs_ws[tid];
    __syncthreads();

    const int nl = tid & 63;
    const int n  = blk_o + nl;
    const int b0 = (tid >> 6) * 8;      // each thread: 8 batches x 1 output
    const float scn = sc[n];
    const float bin = bias[n];
    const float* wcn = wc + (size_t)n * NFP;

    float dots[8];
    #pragma unroll
    for (int j = 0; j < 8; j++) dots[j] = 0.f;
    for (int u = 0; u < NFP; u += 4) {
        float4 wv = *(const float4*)(wcn + u);
        #pragma unroll
        for (int j = 0; j < 8; j++) {
            float4 av = *(const float4*)(&act_l[(b0 + j) * NFP + u]);  // LDS broadcast
            dots[j] += av.x * wv.x + av.y * wv.y + av.z * wv.z + av.w * wv.w;
        }
    }

    #pragma unroll
    for (int j = 0; j < 8; j++) {
        const int b = b0 + j;
        const size_t idx = (size_t)b * OUT_F + n;
        int s = part[idx];
        #pragma unroll
        for (int k = 1; k < KC; k++) s += part[((size_t)k * NB + b) * OUT_F + n];
        out[idx] = (float)s * xs_l[b] * scn + dots[j] + bin;
    }
}

extern "C" void kernel_launch(void* const* d_in, const int* in_sizes, int n_in,
                              void* d_out, int out_size, void* d_ws, size_t ws_size,
                              hipStream_t stream) {
    const float* x    = (const float*)d_in[0];
    const int*   wgt  = (const int*)d_in[1];
    const float* scol = (const float*)d_in[2];
    const float* wch  = (const float*)d_in[3];
    const float* bias = (const float*)d_in[4];
    const int*   ind  = (const int*)d_in[5];
    float* out = (float*)d_out;

    int*   q_pk = (int*)((char*)d_ws + WS_QPK);
    float* xs   = (float*)((char*)d_ws + WS_XS);
    float* act  = (float*)((char*)d_ws + WS_ACT);
    int*   part = (int*)((char*)d_ws + WS_PART);
    int*   w_pk = (int*)((char*)d_ws + WS_WPK);

    repack_kernel<<<2048, 256, 0, stream>>>(wgt, w_pk);
    quant_kernel<<<NB, 256, 0, stream>>>(x, ind, q_pk, xs, act);
    gemm_kernel<<<(OUT_F / OT) * KC, 128, 0, stream>>>(w_pk, q_pk, part);
    epilogue_kernel<<<OUT_F / 64, 256, 0, stream>>>(part, xs, act, scol, wch, bias, out);
}

// Round 3
// 1261.573 us; speedup vs baseline: 1.0270x; 1.0270x over previous
//
#include <hip/hip_runtime.h>
#include <hip/hip_fp16.h>

#define IN_F   8192
#define OUT_F  28672
#define NFP    128
#define NB     32            // B*S rows
#define KQTOT  (IN_F / 4)    // 2048 packed dwords per batch row

#define KC     8             // split-K factor
#define KCHUNK (IN_F / KC)   // 1024 k per block
#define NSTEP  (KCHUNK / 32) // 32 MFMA steps per wave

// ws layout (bytes):
//   q_pk : int  [NB][KQTOT]                       [0, 262144)
//   xs   : float[32]                              [262144, ...)
//   act  : float[32][128]                         [263168, 279552)
//   part : int  [KC][NB][OUT_F] (29,360,128 B)    [524288, 29884416)
#define WS_QPK  0
#define WS_XS   262144
#define WS_ACT  263168
#define WS_PART 524288

typedef int v4i  __attribute__((ext_vector_type(4)));
typedef int v16i __attribute__((ext_vector_type(16)));

__device__ __forceinline__ int pack8(int4 v) {
    return (v.x & 0xFF) | ((v.y & 0xFF) << 8) | ((v.z & 0xFF) << 16) | (v.w << 24);
}

// ---------------- Kernel A: dynamic quantization (unchanged) ----------------
__global__ __launch_bounds__(256) void quant_kernel(
    const float* __restrict__ x, const int* __restrict__ ind,
    int* __restrict__ q_pk, float* __restrict__ xs_out,
    float* __restrict__ act_out)
{
    __shared__ unsigned char flags[IN_F];   // 8 KB
    __shared__ float redbuf[4];
    __shared__ float xs_sh;
    const int tid = threadIdx.x;
    const int b = blockIdx.x;

    int* fl4 = (int*)flags;
    for (int i = tid; i < IN_F / 4; i += 256) fl4[i] = 0;
    __syncthreads();
    if (tid < NFP) flags[ind[tid]] = 1;
    __syncthreads();

    const float* xrow = x + (size_t)b * IN_F;
    const float4* x4 = (const float4*)xrow;
    float mx = 0.f;
    for (int c = tid; c < IN_F / 4; c += 256) {
        float4 v = x4[c];
        int fw = fl4[c];
        if (!(fw & 0x000000FF)) mx = fmaxf(mx, fabsf(v.x));
        if (!(fw & 0x0000FF00)) mx = fmaxf(mx, fabsf(v.y));
        if (!(fw & 0x00FF0000)) mx = fmaxf(mx, fabsf(v.z));
        if (!(fw & 0xFF000000)) mx = fmaxf(mx, fabsf(v.w));
    }
    #pragma unroll
    for (int off = 32; off > 0; off >>= 1) {
        float o = __shfl_down(mx, off, 64);
        mx = o > mx ? o : mx;
    }
    if ((tid & 63) == 0) redbuf[tid >> 6] = mx;
    __syncthreads();
    if (tid == 0) {
        float m = redbuf[0];
        #pragma unroll
        for (int i = 1; i < 4; i++) m = redbuf[i] > m ? redbuf[i] : m;
        float xs = __half2float(__float2half_rn(m / 127.0f));   // x_scale = f16(max/127)
        xs_sh = xs;
        xs_out[b] = xs;
    }
    __syncthreads();
    const float xs = xs_sh;

    for (int c = tid; c < IN_F / 4; c += 256) {
        float4 v = x4[c];
        int fw = fl4[c];
        float ee[4];
        ee[0] = (fw & 0x000000FF) ? 0.f : v.x;
        ee[1] = (fw & 0x0000FF00) ? 0.f : v.y;
        ee[2] = (fw & 0x00FF0000) ? 0.f : v.z;
        ee[3] = (fw & 0xFF000000) ? 0.f : v.w;
        int pk = 0;
        #pragma unroll
        for (int j = 0; j < 4; j++) {
            float qf = __half2float(__float2half_rn(ee[j] / xs));
            float r = rintf(qf);
            r = fminf(fmaxf(r, -128.f), 127.f);
            int qi = (int)r;
            pk |= (qi & 0xFF) << (8 * j);
        }
        q_pk[(size_t)b * KQTOT + c] = pk;
    }
    if (tid < NFP) act_out[b * NFP + tid] = xrow[ind[tid]];
}

// ---------------- Kernel B: barrier-free direct-fragment MFMA GEMM ----------------
// No LDS. Each wave owns 32 output cols x 32 batches for one K-chunk.
// B-fragments (weights) are loaded straight from global int32 and packed
// in-register: each weight element feeds exactly one lane, so LDS staging
// had zero reuse to exploit. A-fragments come from q_pk (256 KB, L2-hot).
// Fragment k-order matches the verified LDS path of R0-R2:
//   frag dword d (d=0..3) = packed k bytes [32s + 16*half + 4d .. +3]
__global__ __launch_bounds__(256) void gemm_kernel(
    const int* __restrict__ w, const int* __restrict__ q_pk,
    int* __restrict__ part)
{
    const int tid  = threadIdx.x;
    const int wv   = tid >> 6;      // wave 0..3 -> col group
    const int lane = tid & 63;
    const int nl   = lane & 31;     // output col within wave tile
    const int half = lane >> 5;     // k-half selector

    const int kc = blockIdx.x & (KC - 1);
    const int ng = blockIdx.x >> 3;          // KC == 8
    const int n  = ng * 128 + wv * 32 + nl;  // this lane's output feature
    const int kbase = kc * KCHUNK;

    // row n, int32 k index base for this lane's half
    const int* wrow  = w + (size_t)n * IN_F + kbase + 16 * half;
    // q row nl, packed-dword base for this lane's half
    const int* qbase = q_pk + (size_t)nl * KQTOT + (kbase >> 2) + 4 * half;

    v16i acc;
    #pragma unroll
    for (int r = 0; r < 16; r++) acc[r] = 0;

    #pragma unroll 4
    for (int s = 0; s < NSTEP; ++s) {
        const int* ws_ = wrow + 32 * s;
        int4 a0 = *(const int4*)(ws_ + 0);
        int4 a1 = *(const int4*)(ws_ + 4);
        int4 a2 = *(const int4*)(ws_ + 8);
        int4 a3 = *(const int4*)(ws_ + 12);
        v4i afrag = *(const v4i*)(qbase + 8 * s);   // 16 B from L2-hot q
        v4i bfrag;
        bfrag[0] = pack8(a0);
        bfrag[1] = pack8(a1);
        bfrag[2] = pack8(a2);
        bfrag[3] = pack8(a3);
        acc = __builtin_amdgcn_mfma_i32_32x32x32_i8(afrag, bfrag, acc, 0, 0, 0);
    }

    // int32 partials (exact); epilogue reduces across kc
    #pragma unroll
    for (int r = 0; r < 16; r++) {
        int b = (r & 3) + 8 * (r >> 2) + 4 * half;   // C/D row = batch
        part[((size_t)kc * NB + b) * OUT_F + n] = acc[r];
    }
}

// ---------------- Kernel C: reduce partials + f32 epilogue ----------------
__global__ __launch_bounds__(256) void epilogue_kernel(
    const int* __restrict__ part, const float* __restrict__ xs_ws,
    const float* __restrict__ act_ws, const float* __restrict__ sc,
    const float* __restrict__ wc, const float* __restrict__ bias,
    float* __restrict__ out)
{
    __shared__ float act_l[NB * NFP];   // 16 KB
    __shared__ float xs_l[NB];
    const int tid = threadIdx.x;
    const int blk_o = blockIdx.x * 64;

    for (int i = tid; i < NB * NFP; i += 256) act_l[i] = act_ws[i];
    if (tid < NB) xs_l[tid] = xs_ws[tid];
    __syncthreads();

    const int nl = tid & 63;
    const int n  = blk_o + nl;
    const int b0 = (tid >> 6) * 8;      // each thread: 8 batches x 1 output
    const float scn = sc[n];
    const float bin = bias[n];
    const float* wcn = wc + (size_t)n * NFP;

    float dots[8];
    #pragma unroll
    for (int j = 0; j < 8; j++) dots[j] = 0.f;
    for (int u = 0; u < NFP; u += 4) {
        float4 wv = *(const float4*)(wcn + u);
        #pragma unroll
        for (int j = 0; j < 8; j++) {
            float4 av = *(const float4*)(&act_l[(b0 + j) * NFP + u]);  // LDS broadcast
            dots[j] += av.x * wv.x + av.y * wv.y + av.z * wv.z + av.w * wv.w;
        }
    }

    #pragma unroll
    for (int j = 0; j < 8; j++) {
        const int b = b0 + j;
        const size_t idx = (size_t)b * OUT_F + n;
        int s = part[idx];
        #pragma unroll
        for (int k = 1; k < KC; k++) s += part[((size_t)k * NB + b) * OUT_F + n];
        out[idx] = (float)s * xs_l[b] * scn + dots[j] + bin;
    }
}

extern "C" void kernel_launch(void* const* d_in, const int* in_sizes, int n_in,
                              void* d_out, int out_size, void* d_ws, size_t ws_size,
                              hipStream_t stream) {
    const float* x    = (const float*)d_in[0];
    const int*   wgt  = (const int*)d_in[1];
    const float* scol = (const float*)d_in[2];
    const float* wch  = (const float*)d_in[3];
    const float* bias = (const float*)d_in[4];
    const int*   ind  = (const int*)d_in[5];
    float* out = (float*)d_out;

    int*   q_pk = (int*)((char*)d_ws + WS_QPK);
    float* xs   = (float*)((char*)d_ws + WS_XS);
    float* act  = (float*)((char*)d_ws + WS_ACT);
    int*   part = (int*)((char*)d_ws + WS_PART);

    quant_kernel<<<NB, 256, 0, stream>>>(x, ind, q_pk, xs, act);
    gemm_kernel<<<(OUT_F / 128) * KC, 256, 0, stream>>>(wgt, q_pk, part);
    epilogue_kernel<<<OUT_F / 64, 256, 0, stream>>>(part, xs, act, scol, wch, bias, out);
}

// Round 4
// 1204.269 us; speedup vs baseline: 1.0758x; 1.0476x over previous
//
#include <hip/hip_runtime.h>
#include <hip/hip_fp16.h>

#define IN_F   8192
#define OUT_F  28672
#define NFP    128
#define NB     32            // B*S rows
#define KQTOT  (IN_F / 4)    // 2048 packed dwords per batch row

// ws layout (bytes):
//   q_pk : int  [NB][KQTOT]   [0, 262144)
//   xs   : float[32]          [262144, ...)
//   act  : float[32][128]     [263168, 279552)
#define WS_QPK  0
#define WS_XS   262144
#define WS_ACT  263168

typedef int v4i  __attribute__((ext_vector_type(4)));
typedef int v16i __attribute__((ext_vector_type(16)));

__device__ __forceinline__ int pack8(int4 v) {
    return (v.x & 0xFF) | ((v.y & 0xFF) << 8) | ((v.z & 0xFF) << 16) | (v.w << 24);
}

// ---------------- Kernel A: dynamic quantization (unchanged, proven) ----------------
__global__ __launch_bounds__(256) void quant_kernel(
    const float* __restrict__ x, const int* __restrict__ ind,
    int* __restrict__ q_pk, float* __restrict__ xs_out,
    float* __restrict__ act_out)
{
    __shared__ unsigned char flags[IN_F];   // 8 KB
    __shared__ float redbuf[4];
    __shared__ float xs_sh;
    const int tid = threadIdx.x;
    const int b = blockIdx.x;

    int* fl4 = (int*)flags;
    for (int i = tid; i < IN_F / 4; i += 256) fl4[i] = 0;
    __syncthreads();
    if (tid < NFP) flags[ind[tid]] = 1;
    __syncthreads();

    const float* xrow = x + (size_t)b * IN_F;
    const float4* x4 = (const float4*)xrow;
    float mx = 0.f;
    for (int c = tid; c < IN_F / 4; c += 256) {
        float4 v = x4[c];
        int fw = fl4[c];
        if (!(fw & 0x000000FF)) mx = fmaxf(mx, fabsf(v.x));
        if (!(fw & 0x0000FF00)) mx = fmaxf(mx, fabsf(v.y));
        if (!(fw & 0x00FF0000)) mx = fmaxf(mx, fabsf(v.z));
        if (!(fw & 0xFF000000)) mx = fmaxf(mx, fabsf(v.w));
    }
    #pragma unroll
    for (int off = 32; off > 0; off >>= 1) {
        float o = __shfl_down(mx, off, 64);
        mx = o > mx ? o : mx;
    }
    if ((tid & 63) == 0) redbuf[tid >> 6] = mx;
    __syncthreads();
    if (tid == 0) {
        float m = redbuf[0];
        #pragma unroll
        for (int i = 1; i < 4; i++) m = redbuf[i] > m ? redbuf[i] : m;
        float xs = __half2float(__float2half_rn(m / 127.0f));   // x_scale = f16(max/127)
        xs_sh = xs;
        xs_out[b] = xs;
    }
    __syncthreads();
    const float xs = xs_sh;

    for (int c = tid; c < IN_F / 4; c += 256) {
        float4 v = x4[c];
        int fw = fl4[c];
        float ee[4];
        ee[0] = (fw & 0x000000FF) ? 0.f : v.x;
        ee[1] = (fw & 0x0000FF00) ? 0.f : v.y;
        ee[2] = (fw & 0x00FF0000) ? 0.f : v.z;
        ee[3] = (fw & 0xFF000000) ? 0.f : v.w;
        int pk = 0;
        #pragma unroll
        for (int j = 0; j < 4; j++) {
            float qf = __half2float(__float2half_rn(ee[j] / xs));
            float r = rintf(qf);
            r = fminf(fmaxf(r, -128.f), 127.f);
            int qi = (int)r;
            pk |= (qi & 0xFF) << (8 * j);
        }
        q_pk[(size_t)b * KQTOT + c] = pk;
    }
    if (tid < NFP) act_out[b * NFP + tid] = xrow[ind[tid]];
}

// ---------------- Kernel B: fused MFMA GEMM + epilogue ----------------
// R0 structure (proven-correct layouts) with: 4 waves/block (2 col-groups x
// 2 k-groups -> 12 waves/CU resident at 3 blocks/CU), KT=512 (half the
// barriers of R0), epilogue fused (no part traffic, no 3rd dispatch).
#define KT    512
#define NT    (IN_F / KT)    // 16 tiles
#define WROW  132            // 128 dwords + 4 pad (stride % 32 == 4, as proven)
#define QROW  132

__global__ __launch_bounds__(256) void gemm_kernel(
    const int* __restrict__ w, const int* __restrict__ q_pk,
    const float* __restrict__ xs_ws, const float* __restrict__ act_ws,
    const float* __restrict__ sc, const float* __restrict__ wc,
    const float* __restrict__ bias, float* __restrict__ out)
{
    __shared__ int w_p[64 * WROW] __attribute__((aligned(16)));   // 33792 B
    __shared__ int q_t[32 * QROW] __attribute__((aligned(16)));   // 16896 B

    const int tid  = threadIdx.x;
    const int wv   = tid >> 6;
    const int lane = tid & 63;
    const int nl   = lane & 31;     // output col within wave tile
    const int half = lane >> 5;     // k-half selector within 32-k MFMA step
    const int cg   = wv & 1;        // col group (0: cols 0-31, 1: cols 32-63)
    const int kg   = wv >> 1;       // k group (0: k 0-255 of tile, 1: k 256-511)

    const int blk_o = blockIdx.x * 64;
    const int n = blk_o + cg * 32 + nl;

    v16i acc;
    #pragma unroll
    for (int r = 0; r < 16; r++) acc[r] = 0;

    for (int t = 0; t < NT; ++t) {
        const int k0 = t * KT;
        // stage W tile: 64 rows x 512 k (int32) -> packed int8.
        // 32 threads cover one row's 2 KB; proven stride-64B 4x16B pattern.
        #pragma unroll 2
        for (int i = 0; i < 8; i++) {
            int u  = i * 256 + tid;
            int r  = u >> 5;          // row 0..63
            int c8 = u & 31;          // 16-B packed chunk 0..31
            const int* src = w + (size_t)(blk_o + r) * IN_F + k0 + c8 * 16;
            int4 a = *(const int4*)(src + 0);
            int4 b = *(const int4*)(src + 4);
            int4 c = *(const int4*)(src + 8);
            int4 d = *(const int4*)(src + 12);
            int4 pk = make_int4(pack8(a), pack8(b), pack8(c), pack8(d));
            *(int4*)&w_p[r * WROW + c8 * 4] = pk;
        }
        // stage q tile: 32 batches x 128 packed dwords
        #pragma unroll
        for (int i = 0; i < 4; i++) {
            int u  = i * 256 + tid;
            int bb = u >> 5;          // batch 0..31
            int c8 = u & 31;
            int4 v = *(const int4*)(q_pk + (size_t)bb * KQTOT + (k0 >> 2) + c8 * 4);
            *(int4*)&q_t[bb * QROW + c8 * 4] = v;
        }
        __syncthreads();

        // wave (cg,kg): cols cg*32+nl, k-range [kg*256, kg*256+256) of tile.
        // frag dword order identical to proven path: half*4 + s*8.
        const int kd = kg * 64 + half * 4;
        const int* qrow = &q_t[nl * QROW + kd];
        const int* wrow = &w_p[(cg * 32 + nl) * WROW + kd];
        #pragma unroll
        for (int s = 0; s < 8; s++) {
            v4i a = *(const v4i*)(qrow + 8 * s);   // ds_read_b128
            v4i b = *(const v4i*)(wrow + 8 * s);   // ds_read_b128
            acc = __builtin_amdgcn_mfma_i32_32x32x32_i8(a, b, acc, 0, 0, 0);
        }
        __syncthreads();   // protects LDS for next tile's staging / final reuse
    }

    // ---- cross-wave k-reduce (exact int32) + fused epilogue ----
    int* red = q_t;                       // reuse q LDS (8 KB used)
    if (kg == 1) {
        #pragma unroll
        for (int r = 0; r < 16; r++) red[(cg * 64 + lane) * 16 + r] = acc[r];
    }
    float* act_l = (float*)w_p;           // reuse W LDS (16 KB used)
    for (int i = tid; i < NB * NFP; i += 256) act_l[i] = act_ws[i];
    float* xs_l = (float*)&q_t[2048];
    if (tid < NB) xs_l[tid] = xs_ws[tid];
    __syncthreads();

    if (kg == 0) {
        #pragma unroll
        for (int r = 0; r < 16; r++) acc[r] += red[(cg * 64 + lane) * 16 + r];

        const float scn = sc[n];
        const float bin = bias[n];
        const float* wcn = wc + (size_t)n * NFP;

        float dots[16];
        #pragma unroll
        for (int r = 0; r < 16; r++) dots[r] = 0.f;

        for (int j = 0; j < NFP; j += 4) {
            float4 wv4 = *(const float4*)(wcn + j);
            #pragma unroll
            for (int r = 0; r < 16; r++) {
                int b = (r & 3) + 8 * (r >> 2) + 4 * half;   // C/D row = batch
                float4 av = *(const float4*)(&act_l[b * NFP + j]);  // LDS broadcast
                dots[r] += av.x * wv4.x + av.y * wv4.y + av.z * wv4.z + av.w * wv4.w;
            }
        }

        #pragma unroll
        for (int r = 0; r < 16; r++) {
            int b = (r & 3) + 8 * (r >> 2) + 4 * half;
            out[(size_t)b * OUT_F + n] = (float)acc[r] * xs_l[b] * scn + dots[r] + bin;
        }
    }
}

extern "C" void kernel_launch(void* const* d_in, const int* in_sizes, int n_in,
                              void* d_out, int out_size, void* d_ws, size_t ws_size,
                              hipStream_t stream) {
    const float* x    = (const float*)d_in[0];
    const int*   wgt  = (const int*)d_in[1];
    const float* scol = (const float*)d_in[2];
    const float* wch  = (const float*)d_in[3];
    const float* bias = (const float*)d_in[4];
    const int*   ind  = (const int*)d_in[5];
    float* out = (float*)d_out;

    int*   q_pk = (int*)((char*)d_ws + WS_QPK);
    float* xs   = (float*)((char*)d_ws + WS_XS);
    float* act  = (float*)((char*)d_ws + WS_ACT);

    quant_kernel<<<NB, 256, 0, stream>>>(x, ind, q_pk, xs, act);
    gemm_kernel<<<OUT_F / 64, 256, 0, stream>>>(wgt, q_pk, xs, act, scol, wch, bias, out);
}